// Round 2
// baseline (178.108 us; speedup 1.0000x reference)
//
#include <hip/hip_runtime.h>
#include <hip/hip_bf16.h>

// GraphConv on MI355X — single fused kernel.
// Factorization: edge-MLP layer1 relu(ns[s]@W1t + ns[r]@W1b + b1) -> per-node
// partials P (computed in-block), per-receiver Q; layer2 (64x64) via bf16 MFMA.
// Decoder fused. No workspace, no prep kernel.

typedef __attribute__((ext_vector_type(8))) short bh8;   // 8 x bf16 bits
typedef __attribute__((ext_vector_type(4))) float fv4;   // MFMA accumulator

union AB { bh8 v; __hip_bfloat162 h[4]; };

// grid = 128 b * 8 recv-groups, 256 threads.
// LDS: NSl 4K + Pl 34816 + Qb 4K + ETl 4K + MSG 2K = ~48.5 KB -> 3 blocks/CU.
__global__ __launch_bounds__(256, 3) void fused_kernel(
    const float* __restrict__ ns, const float* __restrict__ et,
    const float* __restrict__ e0w1, const float* __restrict__ e0b1,
    const float* __restrict__ e0w2, const float* __restrict__ e0b2,
    const float* __restrict__ e1w1, const float* __restrict__ e1b1,
    const float* __restrict__ e1w2, const float* __restrict__ e1b2,
    const float* __restrict__ ndw1, const float* __restrict__ ndb1,
    const float* __restrict__ ndw2, const float* __restrict__ ndb2,
    float* __restrict__ out)
{
  __shared__ float NSl[64*16];           // node states of this batch   4096 B
  __shared__ float Pl[2*64*68];          // P partials, stride-68 pad  34816 B (aliased as HD)
  __shared__ float Qb[2*8*64];           // Q + b1 for 8 receivers      4096 B
  __shared__ float ETl[2*8*64];          // edge-type weights           4096 B
  __shared__ float MSG[8*64];            // node messages               2048 B

  int t = threadIdx.x;
  int b = blockIdx.x >> 3, rg = blockIdx.x & 7, r0 = rg*8;
  int w = t >> 6, lane = t & 63, quad = lane >> 4, col = lane & 15;

  // ---- stage ns[b] ----
  ((float4*)NSl)[t] = ((const float4*)(ns + b*1024))[t];
  __syncthreads();

  // ---- compute P[enc][s][h] for all 64 senders ----
  // wave w handles sender group s = w*16..w*16+15; lane's h = lane.
  {
    int h = lane;
#pragma unroll
    for (int enc = 0; enc < 2; ++enc) {
      const float* w1 = enc ? e1w1 : e0w1;
      float wc[16];
#pragma unroll
      for (int k = 0; k < 16; ++k) wc[k] = w1[k*64 + h];     // top rows, col h
      float* pdst = Pl + enc*4352;
#pragma unroll
      for (int si = 0; si < 16; ++si) {
        int s = w*16 + si;
        const float* x = NSl + s*16;                          // LDS broadcast
        float acc = 0.f;
#pragma unroll
        for (int k = 0; k < 16; ++k) acc += wc[k] * x[k];
        pdst[s*68 + h] = acc;
      }
    }
  }
  // ---- compute Q[enc][rl][h] for this block's 8 receivers (+b1) ----
#pragma unroll
  for (int i = 0; i < 4; ++i) {
    int idx = i*256 + t;                  // 0..1023
    int enc = idx >> 9, rem = idx & 511;
    int rl = rem >> 6, h = rem & 63;
    const float* w1 = enc ? e1w1 : e0w1;
    const float* b1 = enc ? e1b1 : e0b1;
    const float* x = NSl + (r0 + rl)*16;                      // wave-uniform
    float acc = b1[h];
#pragma unroll
    for (int k = 0; k < 16; ++k) acc += w1[(16 + k)*64 + h] * x[k];
    Qb[idx] = acc;
  }
  // ---- gather edge-type weights: ET[enc][rl][s] ----
#pragma unroll
  for (int i = 0; i < 4; ++i) {
    int idx = i*256 + t;
    int enc = idx >> 9, rem = idx & 511;
    int rl = rem >> 6, s = rem & 63;
    int r = r0 + rl;
    float v = 0.f;
    if (s != r) {
      int e = s*63 + (r < s ? r : r - 1);
      v = et[(b*4032 + e)*3 + 1 + enc];
    }
    ETl[idx] = v;
  }
  __syncthreads();

  float msgacc[2][4] = {{0.f,0.f,0.f,0.f},{0.f,0.f,0.f,0.f}};

#pragma unroll
  for (int enc = 0; enc < 2; ++enc) {
    // B fragments direct from global (L2-hot): lane holds W2[k=kk*32+quad*8+j][n=nt*16+col]
    const float* w2 = enc ? e1w2 : e0w2;
    const float* b2 = enc ? e1b2 : e0b2;
    bh8 bf[4][2];
    float b2v[4];
#pragma unroll
    for (int nt = 0; nt < 4; ++nt) {
#pragma unroll
      for (int kk = 0; kk < 2; ++kk) {
        const float* base = w2 + (kk*32 + quad*8)*64 + nt*16 + col;
        float f0 = base[0*64], f1 = base[1*64], f2 = base[2*64], f3 = base[3*64];
        float f4 = base[4*64], f5 = base[5*64], f6 = base[6*64], f7 = base[7*64];
        AB bb;
        bb.h[0] = __float22bfloat162_rn(make_float2(f0, f1));
        bb.h[1] = __float22bfloat162_rn(make_float2(f2, f3));
        bb.h[2] = __float22bfloat162_rn(make_float2(f4, f5));
        bb.h[3] = __float22bfloat162_rn(make_float2(f6, f7));
        bf[nt][kk] = bb.v;
      }
      b2v[nt] = b2[nt*16 + col];
    }
#pragma unroll
    for (int rli = 0; rli < 2; ++rli) {
      int rl = w*2 + rli;                 // this wave owns receivers 2w, 2w+1
      const float* qrow = Qb + (enc*8 + rl)*64;
      float4 qa0 = *(const float4*)(qrow + quad*8);
      float4 qa1 = *(const float4*)(qrow + quad*8 + 4);
      float4 qb0 = *(const float4*)(qrow + 32 + quad*8);
      float4 qb1 = *(const float4*)(qrow + 32 + quad*8 + 4);
      const float* etrow = ETl + (enc*8 + rl)*64;
#pragma unroll
      for (int st = 0; st < 4; ++st) {
        const float* prow = Pl + enc*4352 + (st*16 + col)*68;
        float4 pa0 = *(const float4*)(prow + quad*8);
        float4 pa1 = *(const float4*)(prow + quad*8 + 4);
        float4 pb0 = *(const float4*)(prow + 32 + quad*8);
        float4 pb1 = *(const float4*)(prow + 32 + quad*8 + 4);
        // h1 = relu(P[s] + Q[r]) -> bf16 A-fragments, packed cvt
        AB a0, a1;
        a0.h[0] = __float22bfloat162_rn(make_float2(fmaxf(pa0.x + qa0.x, 0.f), fmaxf(pa0.y + qa0.y, 0.f)));
        a0.h[1] = __float22bfloat162_rn(make_float2(fmaxf(pa0.z + qa0.z, 0.f), fmaxf(pa0.w + qa0.w, 0.f)));
        a0.h[2] = __float22bfloat162_rn(make_float2(fmaxf(pa1.x + qa1.x, 0.f), fmaxf(pa1.y + qa1.y, 0.f)));
        a0.h[3] = __float22bfloat162_rn(make_float2(fmaxf(pa1.z + qa1.z, 0.f), fmaxf(pa1.w + qa1.w, 0.f)));
        a1.h[0] = __float22bfloat162_rn(make_float2(fmaxf(pb0.x + qb0.x, 0.f), fmaxf(pb0.y + qb0.y, 0.f)));
        a1.h[1] = __float22bfloat162_rn(make_float2(fmaxf(pb0.z + qb0.z, 0.f), fmaxf(pb0.w + qb0.w, 0.f)));
        a1.h[2] = __float22bfloat162_rn(make_float2(fmaxf(pb1.x + qb1.x, 0.f), fmaxf(pb1.y + qb1.y, 0.f)));
        a1.h[3] = __float22bfloat162_rn(make_float2(fmaxf(pb1.z + qb1.z, 0.f), fmaxf(pb1.w + qb1.w, 0.f)));
        float4 etv = *(const float4*)(etrow + st*16 + quad*4);
#pragma unroll
        for (int nt = 0; nt < 4; ++nt) {
          fv4 acc = {0.f, 0.f, 0.f, 0.f};
          acc = __builtin_amdgcn_mfma_f32_16x16x32_bf16(a0.v, bf[nt][0], acc, 0, 0, 0);
          acc = __builtin_amdgcn_mfma_f32_16x16x32_bf16(a1.v, bf[nt][1], acc, 0, 0, 0);
          // C layout: row(sender) = quad*4+reg, col(h) = col
          float m = msgacc[rli][nt];
          m += etv.x * fmaxf(acc[0] + b2v[nt], 0.f);
          m += etv.y * fmaxf(acc[1] + b2v[nt], 0.f);
          m += etv.z * fmaxf(acc[2] + b2v[nt], 0.f);
          m += etv.w * fmaxf(acc[3] + b2v[nt], 0.f);
          msgacc[rli][nt] = m;
        }
      }
    }
  }
  // quad reduction over senders -> MSG[rl][h]
#pragma unroll
  for (int rli = 0; rli < 2; ++rli) {
#pragma unroll
    for (int nt = 0; nt < 4; ++nt) {
      float v = msgacc[rli][nt];
      v += __shfl_xor(v, 16);
      v += __shfl_xor(v, 32);
      if (lane < 16) MSG[(w*2 + rli)*64 + nt*16 + lane] = v;
    }
  }
  __syncthreads();

  // ---- decoder: relu(relu([ns, msg]@W1+b1)@W2+b2), fp32 ----
  float* HD = Pl;   // alias dead P region
#pragma unroll
  for (int pass = 0; pass < 2; ++pass) {
    int idx = pass*256 + t;              // 0..511 -> (rl, j)
    int rl = idx >> 6, j = idx & 63;
    float acc = ndb1[j];
    const float* x0 = NSl + (r0 + rl)*16;
#pragma unroll
    for (int i = 0; i < 16; ++i) acc += x0[i] * ndw1[i*64 + j];
    const float* mrow = MSG + rl*64;
    for (int i = 0; i < 64; ++i) acc += mrow[i] * ndw1[(16 + i)*64 + j];
    HD[idx] = fmaxf(acc, 0.f);
  }
  __syncthreads();
  if (t < 128) {
    int rl = t >> 4, o = t & 15;
    float acc = ndb2[o];
#pragma unroll
    for (int j = 0; j < 64; ++j) acc += HD[rl*64 + j] * ndw2[j*16 + o];
    out[(b*64 + r0 + rl)*16 + o] = fmaxf(acc, 0.f);
  }
}

extern "C" void kernel_launch(void* const* d_in, const int* in_sizes, int n_in,
                              void* d_out, int out_size, void* d_ws, size_t ws_size,
                              hipStream_t stream) {
  const float* ns   = (const float*)d_in[0];
  const float* et   = (const float*)d_in[1];
  const float* e0w1 = (const float*)d_in[2];
  const float* e0b1 = (const float*)d_in[3];
  const float* e0w2 = (const float*)d_in[4];
  const float* e0b2 = (const float*)d_in[5];
  const float* e1w1 = (const float*)d_in[6];
  const float* e1b1 = (const float*)d_in[7];
  const float* e1w2 = (const float*)d_in[8];
  const float* e1b2 = (const float*)d_in[9];
  const float* ndw1 = (const float*)d_in[10];
  const float* ndb1 = (const float*)d_in[11];
  const float* ndw2 = (const float*)d_in[12];
  const float* ndb2 = (const float*)d_in[13];

  fused_kernel<<<1024, 256, 0, stream>>>(ns, et,
                                         e0w1, e0b1, e0w2, e0b2,
                                         e1w1, e1b1, e1w2, e1b2,
                                         ndw1, ndb1, ndw2, ndb2,
                                         (float*)d_out);
}

// Round 3
// 133.373 us; speedup vs baseline: 1.3354x; 1.3354x over previous
//
#include <hip/hip_runtime.h>
#include <hip/hip_bf16.h>

// GraphConv on MI355X — single fused kernel.
// Factorization: edge-MLP layer1 relu(ns[s]@W1t + ns[r]@W1b + b1) -> per-node
// partials P (computed in-block), per-receiver Q; layer2 (64x64) via bf16 MFMA.
// Decoder fused. No workspace, no prep kernel.
// NOTE: no min-waves clamp in __launch_bounds__ — round 2 showed (256,3)
// forces spills (211 MB scratch writes). Natural allocation ~188 VGPR, no spill.

typedef __attribute__((ext_vector_type(8))) short bh8;   // 8 x bf16 bits
typedef __attribute__((ext_vector_type(4))) float fv4;   // MFMA accumulator

union AB { bh8 v; __hip_bfloat162 h[4]; };

// grid = 128 b * 8 recv-groups, 256 threads.
// LDS: NSl 4K + Pl 34816 + Qb 4K + ETl 4K + MSG 2K = 48 KB -> 2 blocks/CU (VGPR-bound anyway).
__global__ __launch_bounds__(256) void fused_kernel(
    const float* __restrict__ ns, const float* __restrict__ et,
    const float* __restrict__ e0w1, const float* __restrict__ e0b1,
    const float* __restrict__ e0w2, const float* __restrict__ e0b2,
    const float* __restrict__ e1w1, const float* __restrict__ e1b1,
    const float* __restrict__ e1w2, const float* __restrict__ e1b2,
    const float* __restrict__ ndw1, const float* __restrict__ ndb1,
    const float* __restrict__ ndw2, const float* __restrict__ ndb2,
    float* __restrict__ out)
{
  __shared__ float NSl[64*16];           // node states of this batch   4096 B
  __shared__ float Pl[2*64*68];          // P partials, stride-68 pad  34816 B (aliased as HD)
  __shared__ float Qb[2*8*64];           // Q + b1 for 8 receivers      4096 B
  __shared__ float ETl[2*8*64];          // edge-type weights [enc][rl][s] 4096 B
  __shared__ float MSG[8*64];            // node messages               2048 B

  int t = threadIdx.x;
  int b = blockIdx.x >> 3, rg = blockIdx.x & 7, r0 = rg*8;
  int w = t >> 6, lane = t & 63, quad = lane >> 4, col = lane & 15;

  // ---- stage ns[b] ----
  ((float4*)NSl)[t] = ((const float4*)(ns + b*1024))[t];
  __syncthreads();

  // ---- compute P[enc][s][h] for all 64 senders ----
  // wave w handles sender group s = w*16..w*16+15; lane's h = lane.
  {
    int h = lane;
#pragma unroll
    for (int enc = 0; enc < 2; ++enc) {
      const float* w1 = enc ? e1w1 : e0w1;
      float wc[16];
#pragma unroll
      for (int k = 0; k < 16; ++k) wc[k] = w1[k*64 + h];     // top rows, col h
      float* pdst = Pl + enc*4352;
#pragma unroll
      for (int si = 0; si < 16; ++si) {
        int s = w*16 + si;
        const float* x = NSl + s*16;                          // LDS broadcast
        float acc = 0.f;
#pragma unroll
        for (int k = 0; k < 16; ++k) acc += wc[k] * x[k];
        pdst[s*68 + h] = acc;
      }
    }
  }
  // ---- compute Q[enc][rl][h] for this block's 8 receivers (+b1) ----
#pragma unroll
  for (int i = 0; i < 4; ++i) {
    int idx = i*256 + t;                  // 0..1023
    int enc = idx >> 9, rem = idx & 511;
    int rl = rem >> 6, h = rem & 63;
    const float* w1 = enc ? e1w1 : e0w1;
    const float* b1 = enc ? e1b1 : e0b1;
    const float* x = NSl + (r0 + rl)*16;                      // wave-uniform
    float acc = b1[h];
#pragma unroll
    for (int k = 0; k < 16; ++k) acc += w1[(16 + k)*64 + h] * x[k];
    Qb[idx] = acc;
  }
  // ---- gather edge-type weights, coalesced along edge index ----
  // idx -> (s, rl): consecutive lanes hit consecutive edges (12 B stride).
#pragma unroll
  for (int i = 0; i < 2; ++i) {
    int idx = i*256 + t;                  // 0..511
    int s = idx >> 3, rl = idx & 7;
    int r = r0 + rl;
    float v0 = 0.f, v1 = 0.f;
    if (s != r) {
      int pos = r - (r > s ? 1 : 0);
      const float* base = et + (b*4032 + s*63 + pos)*3;
      v0 = base[1]; v1 = base[2];
    }
    ETl[rl*64 + s] = v0;
    ETl[512 + rl*64 + s] = v1;
  }
  __syncthreads();

  float msgacc[2][4] = {{0.f,0.f,0.f,0.f},{0.f,0.f,0.f,0.f}};

#pragma unroll
  for (int enc = 0; enc < 2; ++enc) {
    // B fragments direct from global (L2-hot): lane holds W2[k=kk*32+quad*8+j][n=nt*16+col]
    const float* w2 = enc ? e1w2 : e0w2;
    const float* b2 = enc ? e1b2 : e0b2;
    bh8 bf[4][2];
    float b2v[4];
#pragma unroll
    for (int nt = 0; nt < 4; ++nt) {
#pragma unroll
      for (int kk = 0; kk < 2; ++kk) {
        const float* base = w2 + (kk*32 + quad*8)*64 + nt*16 + col;
        float f0 = base[0*64], f1 = base[1*64], f2 = base[2*64], f3 = base[3*64];
        float f4 = base[4*64], f5 = base[5*64], f6 = base[6*64], f7 = base[7*64];
        AB bb;
        bb.h[0] = __float22bfloat162_rn(make_float2(f0, f1));
        bb.h[1] = __float22bfloat162_rn(make_float2(f2, f3));
        bb.h[2] = __float22bfloat162_rn(make_float2(f4, f5));
        bb.h[3] = __float22bfloat162_rn(make_float2(f6, f7));
        bf[nt][kk] = bb.v;
      }
      b2v[nt] = b2[nt*16 + col];
    }
#pragma unroll
    for (int rli = 0; rli < 2; ++rli) {
      int rl = w*2 + rli;                 // this wave owns receivers 2w, 2w+1
      const float* qrow = Qb + (enc*8 + rl)*64;
      float4 qa0 = *(const float4*)(qrow + quad*8);
      float4 qa1 = *(const float4*)(qrow + quad*8 + 4);
      float4 qb0 = *(const float4*)(qrow + 32 + quad*8);
      float4 qb1 = *(const float4*)(qrow + 32 + quad*8 + 4);
      const float* etrow = ETl + (enc*8 + rl)*64;
#pragma unroll
      for (int st = 0; st < 4; ++st) {
        const float* prow = Pl + enc*4352 + (st*16 + col)*68;
        float4 pa0 = *(const float4*)(prow + quad*8);
        float4 pa1 = *(const float4*)(prow + quad*8 + 4);
        float4 pb0 = *(const float4*)(prow + 32 + quad*8);
        float4 pb1 = *(const float4*)(prow + 32 + quad*8 + 4);
        // h1 = relu(P[s] + Q[r]) -> bf16 A-fragments, packed cvt
        AB a0, a1;
        a0.h[0] = __float22bfloat162_rn(make_float2(fmaxf(pa0.x + qa0.x, 0.f), fmaxf(pa0.y + qa0.y, 0.f)));
        a0.h[1] = __float22bfloat162_rn(make_float2(fmaxf(pa0.z + qa0.z, 0.f), fmaxf(pa0.w + qa0.w, 0.f)));
        a0.h[2] = __float22bfloat162_rn(make_float2(fmaxf(pa1.x + qa1.x, 0.f), fmaxf(pa1.y + qa1.y, 0.f)));
        a0.h[3] = __float22bfloat162_rn(make_float2(fmaxf(pa1.z + qa1.z, 0.f), fmaxf(pa1.w + qa1.w, 0.f)));
        a1.h[0] = __float22bfloat162_rn(make_float2(fmaxf(pb0.x + qb0.x, 0.f), fmaxf(pb0.y + qb0.y, 0.f)));
        a1.h[1] = __float22bfloat162_rn(make_float2(fmaxf(pb0.z + qb0.z, 0.f), fmaxf(pb0.w + qb0.w, 0.f)));
        a1.h[2] = __float22bfloat162_rn(make_float2(fmaxf(pb1.x + qb1.x, 0.f), fmaxf(pb1.y + qb1.y, 0.f)));
        a1.h[3] = __float22bfloat162_rn(make_float2(fmaxf(pb1.z + qb1.z, 0.f), fmaxf(pb1.w + qb1.w, 0.f)));
        float4 etv = *(const float4*)(etrow + st*16 + quad*4);
#pragma unroll
        for (int nt = 0; nt < 4; ++nt) {
          // b2 folded into accumulator init: final acc = h2_preact + b2
          fv4 acc = {b2v[nt], b2v[nt], b2v[nt], b2v[nt]};
          acc = __builtin_amdgcn_mfma_f32_16x16x32_bf16(a0.v, bf[nt][0], acc, 0, 0, 0);
          acc = __builtin_amdgcn_mfma_f32_16x16x32_bf16(a1.v, bf[nt][1], acc, 0, 0, 0);
          // C layout: row(sender) = quad*4+reg, col(h) = col
          float m = msgacc[rli][nt];
          m += etv.x * fmaxf(acc[0], 0.f);
          m += etv.y * fmaxf(acc[1], 0.f);
          m += etv.z * fmaxf(acc[2], 0.f);
          m += etv.w * fmaxf(acc[3], 0.f);
          msgacc[rli][nt] = m;
        }
      }
    }
  }
  // quad reduction over senders -> MSG[rl][h]
#pragma unroll
  for (int rli = 0; rli < 2; ++rli) {
#pragma unroll
    for (int nt = 0; nt < 4; ++nt) {
      float v = msgacc[rli][nt];
      v += __shfl_xor(v, 16);
      v += __shfl_xor(v, 32);
      if (lane < 16) MSG[(w*2 + rli)*64 + nt*16 + lane] = v;
    }
  }
  __syncthreads();

  // ---- decoder: relu(relu([ns, msg]@W1+b1)@W2+b2), fp32 ----
  float* HD = Pl;   // alias dead P region
#pragma unroll
  for (int pass = 0; pass < 2; ++pass) {
    int idx = pass*256 + t;              // 0..511 -> (rl, j)
    int rl = idx >> 6, j = idx & 63;
    float acc = ndb1[j];
    const float* x0 = NSl + (r0 + rl)*16;
#pragma unroll
    for (int i = 0; i < 16; ++i) acc += x0[i] * ndw1[i*64 + j];
    const float* mrow = MSG + rl*64;
#pragma unroll
    for (int i = 0; i < 64; ++i) acc += mrow[i] * ndw1[(16 + i)*64 + j];
    HD[idx] = fmaxf(acc, 0.f);
  }
  __syncthreads();
  if (t < 128) {
    int rl = t >> 4, o = t & 15;
    float acc = ndb2[o];
#pragma unroll
    for (int j = 0; j < 64; ++j) acc += HD[rl*64 + j] * ndw2[j*16 + o];
    out[(b*64 + r0 + rl)*16 + o] = fmaxf(acc, 0.f);
  }
}

extern "C" void kernel_launch(void* const* d_in, const int* in_sizes, int n_in,
                              void* d_out, int out_size, void* d_ws, size_t ws_size,
                              hipStream_t stream) {
  const float* ns   = (const float*)d_in[0];
  const float* et   = (const float*)d_in[1];
  const float* e0w1 = (const float*)d_in[2];
  const float* e0b1 = (const float*)d_in[3];
  const float* e0w2 = (const float*)d_in[4];
  const float* e0b2 = (const float*)d_in[5];
  const float* e1w1 = (const float*)d_in[6];
  const float* e1b1 = (const float*)d_in[7];
  const float* e1w2 = (const float*)d_in[8];
  const float* e1b2 = (const float*)d_in[9];
  const float* ndw1 = (const float*)d_in[10];
  const float* ndb1 = (const float*)d_in[11];
  const float* ndw2 = (const float*)d_in[12];
  const float* ndb2 = (const float*)d_in[13];

  fused_kernel<<<1024, 256, 0, stream>>>(ns, et,
                                         e0w1, e0b1, e0w2, e0b2,
                                         e1w1, e1b1, e1w2, e1b2,
                                         ndw1, ndb1, ndw2, ndb2,
                                         (float*)d_out);
}

// Round 4
// 112.274 us; speedup vs baseline: 1.5864x; 1.1879x over previous
//
#include <hip/hip_runtime.h>
#include <hip/hip_bf16.h>

// GraphConv on MI355X — single fused kernel, occupancy-tuned.
// Round-4 changes vs round-3:
//  * P stored in LDS as bf16 (stride-72) -> LDS 48K -> 32K (4+ blocks/CU).
//  * P computed via zero-padded 16x16x32 bf16 MFMA (64x64x16 GEMM), not VALU.
//  * __launch_bounds__(256,4) with rolled enc/rli loops to keep VGPR <= 128
//    WITHOUT spilling (round-2 spill was a cap on inherently fat code;
//    tripwire: WRITE_SIZE must stay ~0.5 MB).

typedef __attribute__((ext_vector_type(8))) short bh8;   // 8 x bf16 bits
typedef __attribute__((ext_vector_type(4))) float fv4;   // MFMA accumulator

union AB { bh8 v; __hip_bfloat162 h[4]; };

// grid = 128 b * 8 recv-groups, 256 threads (4 waves).
__global__ __launch_bounds__(256, 4) void fused_kernel(
    const float* __restrict__ ns, const float* __restrict__ et,
    const float* __restrict__ e0w1, const float* __restrict__ e0b1,
    const float* __restrict__ e0w2, const float* __restrict__ e0b2,
    const float* __restrict__ e1w1, const float* __restrict__ e1b1,
    const float* __restrict__ e1w2, const float* __restrict__ e1b2,
    const float* __restrict__ ndw1, const float* __restrict__ ndb1,
    const float* __restrict__ ndw2, const float* __restrict__ ndb2,
    float* __restrict__ out)
{
  __shared__ float NSl[64*16];                         //  4096 B
  __shared__ __align__(16) __hip_bfloat16 Plh[2*64*72];// 18432 B (aliased as HD later)
  __shared__ float Qb[2*8*64];                         //  4096 B
  __shared__ float ETl[2*8*64];                        //  4096 B
  __shared__ float MSG[8*64];                          //  2048 B
                                                       // total 32768 B

  int t = threadIdx.x;
  int b = blockIdx.x >> 3, rg = blockIdx.x & 7, r0 = rg*8;
  int w = t >> 6, lane = t & 63, quad = lane >> 4, col = lane & 15;

  // ---- stage ns[b] ----
  ((float4*)NSl)[t] = ((const float4*)(ns + b*1024))[t];
  __syncthreads();

  const __hip_bfloat162 zz = __float22bfloat162_rn(make_float2(0.f, 0.f));

  // ---- P[enc][s][h] via MFMA: 64x64x16 GEMM, K zero-padded to 32 ----
  // wave w owns s-tile w*16..w*16+15. A[m=col][k=quad*8+j] = ns[w*16+col][k], k<16.
  {
    AB a;
    if (quad < 2) {
      const float* xr = NSl + (w*16 + col)*16 + quad*8;
      float4 x0 = *(const float4*)xr;
      float4 x1 = *(const float4*)(xr + 4);
      a.h[0] = __float22bfloat162_rn(make_float2(x0.x, x0.y));
      a.h[1] = __float22bfloat162_rn(make_float2(x0.z, x0.w));
      a.h[2] = __float22bfloat162_rn(make_float2(x1.x, x1.y));
      a.h[3] = __float22bfloat162_rn(make_float2(x1.z, x1.w));
    } else {
      a.h[0] = a.h[1] = a.h[2] = a.h[3] = zz;
    }
#pragma unroll 1
    for (int enc = 0; enc < 2; ++enc) {
      const float* w1 = enc ? e1w1 : e0w1;
#pragma unroll
      for (int ht = 0; ht < 4; ++ht) {
        AB bb;
        if (quad < 2) {
#pragma unroll
          for (int j = 0; j < 4; ++j) {
            float f0 = w1[(quad*8 + 2*j    )*64 + ht*16 + col];
            float f1 = w1[(quad*8 + 2*j + 1)*64 + ht*16 + col];
            bb.h[j] = __float22bfloat162_rn(make_float2(f0, f1));
          }
        } else {
          bb.h[0] = bb.h[1] = bb.h[2] = bb.h[3] = zz;
        }
        fv4 acc = {0.f, 0.f, 0.f, 0.f};
        acc = __builtin_amdgcn_mfma_f32_16x16x32_bf16(a.v, bb.v, acc, 0, 0, 0);
        // C: row(s) = quad*4+reg, col(h) = col
        __hip_bfloat16* pd = Plh + enc*4608 + (w*16 + quad*4)*72 + ht*16 + col;
        pd[0*72] = __float2bfloat16(acc[0]);
        pd[1*72] = __float2bfloat16(acc[1]);
        pd[2*72] = __float2bfloat16(acc[2]);
        pd[3*72] = __float2bfloat16(acc[3]);
      }
    }
  }
  // ---- Q[enc][rl][h] for this block's 8 receivers (+b1), fp32 VALU ----
#pragma unroll
  for (int i = 0; i < 4; ++i) {
    int idx = i*256 + t;                  // 0..1023
    int enc = idx >> 9, rem = idx & 511;
    int rl = rem >> 6, h = rem & 63;
    const float* w1 = enc ? e1w1 : e0w1;
    const float* b1 = enc ? e1b1 : e0b1;
    const float* x = NSl + (r0 + rl)*16;
    float acc = b1[h];
#pragma unroll
    for (int k = 0; k < 16; ++k) acc += w1[(16 + k)*64 + h] * x[k];
    Qb[idx] = acc;
  }
  // ---- edge-type weights, coalesced along edge index ----
#pragma unroll
  for (int i = 0; i < 2; ++i) {
    int idx = i*256 + t;                  // 0..511 -> (s, rl)
    int s = idx >> 3, rl = idx & 7;
    int r = r0 + rl;
    float v0 = 0.f, v1 = 0.f;
    if (s != r) {
      int pos = r - (r > s ? 1 : 0);
      const float* base = et + (b*4032 + s*63 + pos)*3;
      v0 = base[1]; v1 = base[2];
    }
    ETl[rl*64 + s] = v0;
    ETl[512 + rl*64 + s] = v1;
  }
  __syncthreads();

  float msgacc[2][4] = {{0.f,0.f,0.f,0.f},{0.f,0.f,0.f,0.f}};

#pragma unroll 1
  for (int enc = 0; enc < 2; ++enc) {
    // B fragments from global (L2-hot): lane holds W2[k=kk*32+quad*8+j][n=nt*16+col]
    const float* w2 = enc ? e1w2 : e0w2;
    const float* b2 = enc ? e1b2 : e0b2;
    bh8 bf[4][2];
    float b2v[4];
#pragma unroll
    for (int nt = 0; nt < 4; ++nt) {
#pragma unroll
      for (int kk = 0; kk < 2; ++kk) {
        const float* base = w2 + (kk*32 + quad*8)*64 + nt*16 + col;
        AB bb;
        bb.h[0] = __float22bfloat162_rn(make_float2(base[0*64], base[1*64]));
        bb.h[1] = __float22bfloat162_rn(make_float2(base[2*64], base[3*64]));
        bb.h[2] = __float22bfloat162_rn(make_float2(base[4*64], base[5*64]));
        bb.h[3] = __float22bfloat162_rn(make_float2(base[6*64], base[7*64]));
        bf[nt][kk] = bb.v;
      }
      b2v[nt] = b2[nt*16 + col];
    }
#pragma unroll 1
    for (int rli = 0; rli < 2; ++rli) {
      int rl = w*2 + rli;                 // this wave owns receivers 2w, 2w+1
      const float* qrow = Qb + (enc*8 + rl)*64;
      float4 qa0 = *(const float4*)(qrow + quad*8);
      float4 qa1 = *(const float4*)(qrow + quad*8 + 4);
      float4 qb0 = *(const float4*)(qrow + 32 + quad*8);
      float4 qb1 = *(const float4*)(qrow + 32 + quad*8 + 4);
      const float* etrow = ETl + (enc*8 + rl)*64;
#pragma unroll 2
      for (int st = 0; st < 4; ++st) {
        // A fragment source: h1[s=st*16+col][k], k = kk*32 + quad*8 + j
        const __hip_bfloat16* prow = Plh + enc*4608 + (st*16 + col)*72 + quad*8;
        AB p0, p1;
        p0.v = *(const bh8*)prow;          // k = quad*8 + 0..7
        p1.v = *(const bh8*)(prow + 32);   // k = 32 + quad*8 + 0..7
        AB a0, a1;
        {
          float2 f0 = __bfloat1622float2(p0.h[0]);
          float2 f1 = __bfloat1622float2(p0.h[1]);
          float2 f2 = __bfloat1622float2(p0.h[2]);
          float2 f3 = __bfloat1622float2(p0.h[3]);
          a0.h[0] = __float22bfloat162_rn(make_float2(fmaxf(f0.x + qa0.x, 0.f), fmaxf(f0.y + qa0.y, 0.f)));
          a0.h[1] = __float22bfloat162_rn(make_float2(fmaxf(f1.x + qa0.z, 0.f), fmaxf(f1.y + qa0.w, 0.f)));
          a0.h[2] = __float22bfloat162_rn(make_float2(fmaxf(f2.x + qa1.x, 0.f), fmaxf(f2.y + qa1.y, 0.f)));
          a0.h[3] = __float22bfloat162_rn(make_float2(fmaxf(f3.x + qa1.z, 0.f), fmaxf(f3.y + qa1.w, 0.f)));
          float2 g0 = __bfloat1622float2(p1.h[0]);
          float2 g1 = __bfloat1622float2(p1.h[1]);
          float2 g2 = __bfloat1622float2(p1.h[2]);
          float2 g3 = __bfloat1622float2(p1.h[3]);
          a1.h[0] = __float22bfloat162_rn(make_float2(fmaxf(g0.x + qb0.x, 0.f), fmaxf(g0.y + qb0.y, 0.f)));
          a1.h[1] = __float22bfloat162_rn(make_float2(fmaxf(g1.x + qb0.z, 0.f), fmaxf(g1.y + qb0.w, 0.f)));
          a1.h[2] = __float22bfloat162_rn(make_float2(fmaxf(g2.x + qb1.x, 0.f), fmaxf(g2.y + qb1.y, 0.f)));
          a1.h[3] = __float22bfloat162_rn(make_float2(fmaxf(g3.x + qb1.z, 0.f), fmaxf(g3.y + qb1.w, 0.f)));
        }
        float4 etv = *(const float4*)(etrow + st*16 + quad*4);
#pragma unroll
        for (int nt = 0; nt < 4; ++nt) {
          fv4 acc = {b2v[nt], b2v[nt], b2v[nt], b2v[nt]};   // b2 folded in
          acc = __builtin_amdgcn_mfma_f32_16x16x32_bf16(a0.v, bf[nt][0], acc, 0, 0, 0);
          acc = __builtin_amdgcn_mfma_f32_16x16x32_bf16(a1.v, bf[nt][1], acc, 0, 0, 0);
          // C: row(sender) = quad*4+reg, col(h) = col
          float m = msgacc[rli][nt];
          m += etv.x * fmaxf(acc[0], 0.f);
          m += etv.y * fmaxf(acc[1], 0.f);
          m += etv.z * fmaxf(acc[2], 0.f);
          m += etv.w * fmaxf(acc[3], 0.f);
          msgacc[rli][nt] = m;
        }
      }
    }
  }
  // quad reduction over senders -> MSG[rl][h]
#pragma unroll
  for (int rli = 0; rli < 2; ++rli) {
#pragma unroll
    for (int nt = 0; nt < 4; ++nt) {
      float v = msgacc[rli][nt];
      v += __shfl_xor(v, 16);
      v += __shfl_xor(v, 32);
      if (lane < 16) MSG[(w*2 + rli)*64 + nt*16 + lane] = v;
    }
  }
  __syncthreads();

  // ---- decoder: relu(relu([ns, msg]@W1+b1)@W2+b2), fp32 ----
  float* HD = (float*)Plh;   // alias dead P region
#pragma unroll
  for (int pass = 0; pass < 2; ++pass) {
    int idx = pass*256 + t;              // 0..511 -> (rl, j)
    int rl = idx >> 6, j = idx & 63;
    float acc = ndb1[j];
    const float* x0 = NSl + (r0 + rl)*16;
#pragma unroll
    for (int i = 0; i < 16; ++i) acc += x0[i] * ndw1[i*64 + j];
    const float* mrow = MSG + rl*64;
#pragma unroll
    for (int i = 0; i < 64; ++i) acc += mrow[i] * ndw1[(16 + i)*64 + j];
    HD[idx] = fmaxf(acc, 0.f);
  }
  __syncthreads();
  if (t < 128) {
    int rl = t >> 4, o = t & 15;
    float acc = ndb2[o];
#pragma unroll
    for (int j = 0; j < 64; ++j) acc += HD[rl*64 + j] * ndw2[j*16 + o];
    out[(b*64 + r0 + rl)*16 + o] = fmaxf(acc, 0.f);
  }
}

extern "C" void kernel_launch(void* const* d_in, const int* in_sizes, int n_in,
                              void* d_out, int out_size, void* d_ws, size_t ws_size,
                              hipStream_t stream) {
  const float* ns   = (const float*)d_in[0];
  const float* et   = (const float*)d_in[1];
  const float* e0w1 = (const float*)d_in[2];
  const float* e0b1 = (const float*)d_in[3];
  const float* e0w2 = (const float*)d_in[4];
  const float* e0b2 = (const float*)d_in[5];
  const float* e1w1 = (const float*)d_in[6];
  const float* e1b1 = (const float*)d_in[7];
  const float* e1w2 = (const float*)d_in[8];
  const float* e1b2 = (const float*)d_in[9];
  const float* ndw1 = (const float*)d_in[10];
  const float* ndb1 = (const float*)d_in[11];
  const float* ndw2 = (const float*)d_in[12];
  const float* ndb2 = (const float*)d_in[13];

  fused_kernel<<<1024, 256, 0, stream>>>(ns, et,
                                         e0w1, e0b1, e0w2, e0b2,
                                         e1w1, e1b1, e1w2, e1b2,
                                         ndw1, ndb1, ndw2, ndb2,
                                         (float*)d_out);
}

// Round 6
// 110.792 us; speedup vs baseline: 1.6076x; 1.0134x over previous
//
#include <hip/hip_runtime.h>
#include <hip/hip_fp16.h>

// GraphConv on MI355X — single fused kernel, round 6 (compile fix of round 5).
// vs round 4: h1/h2 pipeline moved from bf16 to fp16 with packed VALU.
//  * relu(P+Q) via v_pk_add_f16 + v_pk_max_f16 (__builtin_elementwise_max on
//    the 8x_Float16 ext-vector; ROCm 7.2 lacks a __half2 __hmax2 overload).
//  * P, Q live in LDS as fp16; W2 B-frags converted to fp16; MFMA is
//    mfma_f32_16x16x32_f16 (same rate & fragment layout as bf16 variant).
//  * LDS 32K -> 30.7K; grid 1024 = 256 CU x 4 blocks stays fully co-resident.

typedef _Float16 hf;
typedef __attribute__((ext_vector_type(8))) _Float16 v8hf;  // 4 VGPRs, MFMA A/B
typedef __attribute__((ext_vector_type(4))) float fv4;      // MFMA accumulator

union ABh { v8hf v; __half2 h[4]; };

// grid = 128 b * 8 recv-groups, 256 threads (4 waves).
__global__ __launch_bounds__(256, 4) void fused_kernel(
    const float* __restrict__ ns, const float* __restrict__ et,
    const float* __restrict__ e0w1, const float* __restrict__ e0b1,
    const float* __restrict__ e0w2, const float* __restrict__ e0b2,
    const float* __restrict__ e1w1, const float* __restrict__ e1b1,
    const float* __restrict__ e1w2, const float* __restrict__ e1b2,
    const float* __restrict__ ndw1, const float* __restrict__ ndb1,
    const float* __restrict__ ndw2, const float* __restrict__ ndb2,
    float* __restrict__ out)
{
  __shared__ float NSl[64*16];                       //  4096 B
  __shared__ __align__(16) _Float16 PlH[2*64*72];    // 18432 B (aliased as HD later)
  __shared__ __align__(16) _Float16 QbH[2*8*64];     //  2048 B
  __shared__ float ETl[2*8*64];                      //  4096 B
  __shared__ float MSG[8*64];                        //  2048 B
                                                     // total 30720 B

  int t = threadIdx.x;
  int b = blockIdx.x >> 3, rg = blockIdx.x & 7, r0 = rg*8;
  int w = t >> 6, lane = t & 63, quad = lane >> 4, col = lane & 15;

  const __half2 z2 = __float22half2_rn(make_float2(0.f, 0.f));
  const v8hf zero8 = {};

  // ---- stage ns[b] ----
  ((float4*)NSl)[t] = ((const float4*)(ns + b*1024))[t];
  __syncthreads();

  // ---- P[enc][s][h] via MFMA: 64x64x16 GEMM, K zero-padded to 32 ----
  // wave w owns s-tile w*16..w*16+15. A[m=col][k=quad*8+j] = ns[w*16+col][k], k<16.
  {
    ABh a;
    if (quad < 2) {
      const float* xr = NSl + (w*16 + col)*16 + quad*8;
      float4 x0 = *(const float4*)xr;
      float4 x1 = *(const float4*)(xr + 4);
      a.h[0] = __float22half2_rn(make_float2(x0.x, x0.y));
      a.h[1] = __float22half2_rn(make_float2(x0.z, x0.w));
      a.h[2] = __float22half2_rn(make_float2(x1.x, x1.y));
      a.h[3] = __float22half2_rn(make_float2(x1.z, x1.w));
    } else {
      a.h[0] = a.h[1] = a.h[2] = a.h[3] = z2;
    }
#pragma unroll 1
    for (int enc = 0; enc < 2; ++enc) {
      const float* w1 = enc ? e1w1 : e0w1;
#pragma unroll
      for (int ht = 0; ht < 4; ++ht) {
        ABh bb;
        if (quad < 2) {
#pragma unroll
          for (int j = 0; j < 4; ++j) {
            float f0 = w1[(quad*8 + 2*j    )*64 + ht*16 + col];
            float f1 = w1[(quad*8 + 2*j + 1)*64 + ht*16 + col];
            bb.h[j] = __float22half2_rn(make_float2(f0, f1));
          }
        } else {
          bb.h[0] = bb.h[1] = bb.h[2] = bb.h[3] = z2;
        }
        fv4 acc = {0.f, 0.f, 0.f, 0.f};
        acc = __builtin_amdgcn_mfma_f32_16x16x32_f16(a.v, bb.v, acc, 0, 0, 0);
        // C: row(s) = quad*4+reg, col(h) = col
        hf* pd = PlH + enc*4608 + (w*16 + quad*4)*72 + ht*16 + col;
        pd[0*72] = (hf)acc[0];
        pd[1*72] = (hf)acc[1];
        pd[2*72] = (hf)acc[2];
        pd[3*72] = (hf)acc[3];
      }
    }
  }
  // ---- Q[enc][rl][h] for this block's 8 receivers (+b1), fp32 VALU -> fp16 ----
#pragma unroll
  for (int i = 0; i < 4; ++i) {
    int idx = i*256 + t;                  // 0..1023
    int enc = idx >> 9, rem = idx & 511;
    int rl = rem >> 6, h = rem & 63;
    const float* w1 = enc ? e1w1 : e0w1;
    const float* b1 = enc ? e1b1 : e0b1;
    const float* x = NSl + (r0 + rl)*16;  // wave-uniform broadcast
    float acc = b1[h];
#pragma unroll
    for (int k = 0; k < 16; ++k) acc += w1[(16 + k)*64 + h] * x[k];
    QbH[idx] = (hf)acc;
  }
  // ---- edge-type weights, coalesced along edge index ----
#pragma unroll
  for (int i = 0; i < 2; ++i) {
    int idx = i*256 + t;                  // 0..511 -> (s, rl)
    int s = idx >> 3, rl = idx & 7;
    int r = r0 + rl;
    float v0 = 0.f, v1 = 0.f;
    if (s != r) {
      int pos = r - (r > s ? 1 : 0);
      const float* base = et + (b*4032 + s*63 + pos)*3;
      v0 = base[1]; v1 = base[2];
    }
    ETl[rl*64 + s] = v0;
    ETl[512 + rl*64 + s] = v1;
  }
  __syncthreads();

  float msgacc[2][4] = {{0.f,0.f,0.f,0.f},{0.f,0.f,0.f,0.f}};

#pragma unroll 1
  for (int enc = 0; enc < 2; ++enc) {
    // B fragments from global (L2-hot): lane holds W2[k=kk*32+quad*8+j][n=nt*16+col]
    const float* w2 = enc ? e1w2 : e0w2;
    const float* b2 = enc ? e1b2 : e0b2;
    v8hf bfr[4][2];
    float b2v[4];
#pragma unroll
    for (int nt = 0; nt < 4; ++nt) {
#pragma unroll
      for (int kk = 0; kk < 2; ++kk) {
        const float* base = w2 + (kk*32 + quad*8)*64 + nt*16 + col;
        ABh bb;
        bb.h[0] = __float22half2_rn(make_float2(base[0*64], base[1*64]));
        bb.h[1] = __float22half2_rn(make_float2(base[2*64], base[3*64]));
        bb.h[2] = __float22half2_rn(make_float2(base[4*64], base[5*64]));
        bb.h[3] = __float22half2_rn(make_float2(base[6*64], base[7*64]));
        bfr[nt][kk] = bb.v;
      }
      b2v[nt] = b2[nt*16 + col];
    }
#pragma unroll 1
    for (int rli = 0; rli < 2; ++rli) {
      int rl = w*2 + rli;                 // this wave owns receivers 2w, 2w+1
      const hf* qrow = QbH + (enc*8 + rl)*64;
      v8hf q0 = *(const v8hf*)(qrow + quad*8);        // k = quad*8 + j
      v8hf q1 = *(const v8hf*)(qrow + 32 + quad*8);   // k = 32 + quad*8 + j
      const float* etrow = ETl + (enc*8 + rl)*64;
#pragma unroll 2
      for (int st = 0; st < 4; ++st) {
        // h1[s=st*16+col][k] = relu(P + Q), packed fp16
        const hf* prow = PlH + enc*4608 + (st*16 + col)*72 + quad*8;
        v8hf p0 = *(const v8hf*)prow;
        v8hf p1 = *(const v8hf*)(prow + 32);
        v8hf s0 = __builtin_elementwise_max(p0 + q0, zero8);  // pk_add + pk_max
        v8hf s1 = __builtin_elementwise_max(p1 + q1, zero8);
        float4 etv = *(const float4*)(etrow + st*16 + quad*4);
#pragma unroll
        for (int nt = 0; nt < 4; ++nt) {
          fv4 acc = {b2v[nt], b2v[nt], b2v[nt], b2v[nt]};   // b2 folded in
          acc = __builtin_amdgcn_mfma_f32_16x16x32_f16(s0, bfr[nt][0], acc, 0, 0, 0);
          acc = __builtin_amdgcn_mfma_f32_16x16x32_f16(s1, bfr[nt][1], acc, 0, 0, 0);
          // C: row(sender) = quad*4+reg, col(h) = col
          float m = msgacc[rli][nt];
          m += etv.x * fmaxf(acc[0], 0.f);
          m += etv.y * fmaxf(acc[1], 0.f);
          m += etv.z * fmaxf(acc[2], 0.f);
          m += etv.w * fmaxf(acc[3], 0.f);
          msgacc[rli][nt] = m;
        }
      }
    }
  }
  // quad reduction over senders -> MSG[rl][h]
#pragma unroll
  for (int rli = 0; rli < 2; ++rli) {
#pragma unroll
    for (int nt = 0; nt < 4; ++nt) {
      float v = msgacc[rli][nt];
      v += __shfl_xor(v, 16);
      v += __shfl_xor(v, 32);
      if (lane < 16) MSG[(w*2 + rli)*64 + nt*16 + lane] = v;
    }
  }
  __syncthreads();

  // ---- decoder: relu(relu([ns, msg]@W1+b1)@W2+b2), fp32 ----
  float* HD = (float*)PlH;   // alias dead P region
#pragma unroll
  for (int pass = 0; pass < 2; ++pass) {
    int idx = pass*256 + t;              // 0..511 -> (rl, j)
    int rl = idx >> 6, j = idx & 63;
    float acc = ndb1[j];
    const float* x0 = NSl + (r0 + rl)*16;
#pragma unroll
    for (int i = 0; i < 16; ++i) acc += x0[i] * ndw1[i*64 + j];
    const float* mrow = MSG + rl*64;
#pragma unroll
    for (int i = 0; i < 64; ++i) acc += mrow[i] * ndw1[(16 + i)*64 + j];
    HD[idx] = fmaxf(acc, 0.f);
  }
  __syncthreads();
  if (t < 128) {
    int rl = t >> 4, o = t & 15;
    float acc = ndb2[o];
#pragma unroll
    for (int j = 0; j < 64; ++j) acc += HD[rl*64 + j] * ndw2[j*16 + o];
    out[(b*64 + r0 + rl)*16 + o] = fmaxf(acc, 0.f);
  }
}

extern "C" void kernel_launch(void* const* d_in, const int* in_sizes, int n_in,
                              void* d_out, int out_size, void* d_ws, size_t ws_size,
                              hipStream_t stream) {
  const float* ns   = (const float*)d_in[0];
  const float* et   = (const float*)d_in[1];
  const float* e0w1 = (const float*)d_in[2];
  const float* e0b1 = (const float*)d_in[3];
  const float* e0w2 = (const float*)d_in[4];
  const float* e0b2 = (const float*)d_in[5];
  const float* e1w1 = (const float*)d_in[6];
  const float* e1b1 = (const float*)d_in[7];
  const float* e1w2 = (const float*)d_in[8];
  const float* e1b2 = (const float*)d_in[9];
  const float* ndw1 = (const float*)d_in[10];
  const float* ndb1 = (const float*)d_in[11];
  const float* ndw2 = (const float*)d_in[12];
  const float* ndb2 = (const float*)d_in[13];

  fused_kernel<<<1024, 256, 0, stream>>>(ns, et,
                                         e0w1, e0b1, e0w2, e0b2,
                                         e1w1, e1b1, e1w2, e1b2,
                                         ndw1, ndb1, ndw2, ndb2,
                                         (float*)d_out);
}

// Round 7
// 109.098 us; speedup vs baseline: 1.6325x; 1.0155x over previous
//
#include <hip/hip_runtime.h>
#include <hip/hip_fp16.h>

// GraphConv on MI355X — single fused kernel, round 7.
// vs round 6: every serial VALU phase replaced by MFMA, barriers 6 -> 2.
//  * Q computed by MFMA reusing the P A-fragments (W1 bottom half); the wave
//    owning the receiver rows writes Q+b1 to LDS.
//  * Decoder done by wave 0 via MFMA: XD = [ns|msg] fp16 (stride 104, K
//    padded 80->96), layer1 = 12 mfma, layer2 = 2 mfma. Garbage A rows 8-15
//    only affect C rows 8-15 (unused) — MFMA rows are independent.
//  * ET/XD global loads issued at kernel top, overlapped with P/Q MFMAs.

typedef _Float16 hf;
typedef __attribute__((ext_vector_type(8))) _Float16 v8hf;  // 4 VGPRs, MFMA A/B
typedef __attribute__((ext_vector_type(4))) float fv4;      // MFMA accumulator

union ABh { v8hf v; __half2 h[4]; };

// grid = 128 b * 8 recv-groups, 256 threads (4 waves).
__global__ __launch_bounds__(256, 4) void fused_kernel(
    const float* __restrict__ ns, const float* __restrict__ et,
    const float* __restrict__ e0w1, const float* __restrict__ e0b1,
    const float* __restrict__ e0w2, const float* __restrict__ e0b2,
    const float* __restrict__ e1w1, const float* __restrict__ e1b1,
    const float* __restrict__ e1w2, const float* __restrict__ e1b2,
    const float* __restrict__ ndw1, const float* __restrict__ ndb1,
    const float* __restrict__ ndw2, const float* __restrict__ ndb2,
    float* __restrict__ out)
{
  __shared__ __align__(16) _Float16 PlH[2*64*72];   // 18432 B  P partials
  __shared__ __align__(16) _Float16 QbH[2*8*64];    //  2048 B  Q + b1
  __shared__ float ETl[2*8*64];                     //  4096 B  edge weights
  // XDH: rows 0-7 = XD ([ns(16) | msg(64) | 0(16)] stride 104);
  //      rows 8-23 = HD2 (decoder hidden, 16 rows so garbage reads stay in-bounds)
  __shared__ __align__(16) _Float16 XDH[24*104];    //  4992 B
                                                    // total 29568 B
  _Float16* XD  = XDH;
  _Float16* HD2 = XDH + 8*104;

  int t = threadIdx.x;
  int b = blockIdx.x >> 3, rg = blockIdx.x & 7, r0 = rg*8;
  int w = t >> 6, lane = t & 63, quad = lane >> 4, col = lane & 15;

  const __half2 z2 = __float22half2_rn(make_float2(0.f, 0.f));
  const v8hf zero8 = {};

  // ======== early global loads (latency overlapped with P/Q MFMAs) ========
  float xnv = 0.f;
  if (t < 128) xnv = ns[(b*64 + r0 + (t >> 4))*16 + (t & 15)];
  float ev0[2], ev1[2];
  int es[2], erl[2];
#pragma unroll
  for (int i = 0; i < 2; ++i) {
    int idx = i*256 + t;                  // 0..511 -> (s, rl)
    int s = idx >> 3, rl = idx & 7;
    es[i] = s; erl[i] = rl;
    int r = r0 + rl;
    float v0 = 0.f, v1 = 0.f;
    if (s != r) {
      int pos = r - (r > s ? 1 : 0);
      const float* base = et + (b*4032 + s*63 + pos)*3;
      v0 = base[1]; v1 = base[2];
    }
    ev0[i] = v0; ev1[i] = v1;
  }

  // ======== P and Q via MFMA: node-tile @ W1 (64x64x16, K padded to 32) ====
  // wave w owns nodes w*16..w*16+15. A[m=col][k=quad*8+j] = ns[node][k], k<16.
  {
    ABh a;
    if (quad < 2) {
      const float* xr = ns + (b*64 + w*16 + col)*16 + quad*8;
      float4 x0 = *(const float4*)xr;
      float4 x1 = *(const float4*)(xr + 4);
      a.h[0] = __float22half2_rn(make_float2(x0.x, x0.y));
      a.h[1] = __float22half2_rn(make_float2(x0.z, x0.w));
      a.h[2] = __float22half2_rn(make_float2(x1.x, x1.y));
      a.h[3] = __float22half2_rn(make_float2(x1.z, x1.w));
    } else {
      a.h[0] = a.h[1] = a.h[2] = a.h[3] = z2;
    }
    bool qwave = (w == (rg >> 1));        // this wave's tile contains r0..r0+7
#pragma unroll 1
    for (int enc = 0; enc < 2; ++enc) {
      const float* w1 = enc ? e1w1 : e0w1;
      const float* b1 = enc ? e1b1 : e0b1;
#pragma unroll
      for (int ht = 0; ht < 4; ++ht) {
        int cc = ht*16 + col;
        ABh bb;
        if (quad < 2) {
#pragma unroll
          for (int j = 0; j < 4; ++j) {
            float f0 = w1[(quad*8 + 2*j    )*64 + cc];
            float f1 = w1[(quad*8 + 2*j + 1)*64 + cc];
            bb.h[j] = __float22half2_rn(make_float2(f0, f1));
          }
        } else {
          bb.h[0] = bb.h[1] = bb.h[2] = bb.h[3] = z2;
        }
        fv4 acc = {0.f, 0.f, 0.f, 0.f};
        acc = __builtin_amdgcn_mfma_f32_16x16x32_f16(a.v, bb.v, acc, 0, 0, 0);
        hf* pd = PlH + enc*4608 + (w*16 + quad*4)*72 + cc;
        pd[0*72] = (hf)acc[0];
        pd[1*72] = (hf)acc[1];
        pd[2*72] = (hf)acc[2];
        pd[3*72] = (hf)acc[3];
      }
      if (qwave) {                        // Q tile: W1 bottom rows 16..31
#pragma unroll
        for (int ht = 0; ht < 4; ++ht) {
          int cc = ht*16 + col;
          ABh bb;
          if (quad < 2) {
#pragma unroll
            for (int j = 0; j < 4; ++j) {
              float f0 = w1[(16 + quad*8 + 2*j    )*64 + cc];
              float f1 = w1[(16 + quad*8 + 2*j + 1)*64 + cc];
              bb.h[j] = __float22half2_rn(make_float2(f0, f1));
            }
          } else {
            bb.h[0] = bb.h[1] = bb.h[2] = bb.h[3] = z2;
          }
          fv4 acc = {0.f, 0.f, 0.f, 0.f};
          acc = __builtin_amdgcn_mfma_f32_16x16x32_f16(a.v, bb.v, acc, 0, 0, 0);
          float b1v = b1[cc];
#pragma unroll
          for (int rr = 0; rr < 4; ++rr) {
            int local = quad*4 + rr;      // node = w*16 + local
            if ((local >> 3) == (rg & 1)) // rows r0..r0+7 of this tile
              QbH[enc*512 + (local & 7)*64 + cc] = (hf)(acc[rr] + b1v);
          }
        }
      }
    }
  }
  // ---- store staged globals to LDS ----
  if (t < 128) {
    int rl = t >> 4, k = t & 15;
    XD[rl*104 + k] = (hf)xnv;             // ns part
    XD[rl*104 + 80 + k] = (hf)0.f;        // zero pad cols 80..95
  }
#pragma unroll
  for (int i = 0; i < 2; ++i) {
    ETl[erl[i]*64 + es[i]] = ev0[i];
    ETl[512 + erl[i]*64 + es[i]] = ev1[i];
  }
  __syncthreads();                        // barrier #1

  // ======== main loop: h2 = relu(h1 @ W2 + b2), et-weighted sum ========
  float msgacc[2][4] = {{0.f,0.f,0.f,0.f},{0.f,0.f,0.f,0.f}};

#pragma unroll 1
  for (int enc = 0; enc < 2; ++enc) {
    const float* w2 = enc ? e1w2 : e0w2;
    const float* b2 = enc ? e1b2 : e0b2;
    v8hf bfr[4][2];
    float b2v[4];
#pragma unroll
    for (int nt = 0; nt < 4; ++nt) {
#pragma unroll
      for (int kk = 0; kk < 2; ++kk) {
        const float* base = w2 + (kk*32 + quad*8)*64 + nt*16 + col;
        ABh bb;
        bb.h[0] = __float22half2_rn(make_float2(base[0*64], base[1*64]));
        bb.h[1] = __float22half2_rn(make_float2(base[2*64], base[3*64]));
        bb.h[2] = __float22half2_rn(make_float2(base[4*64], base[5*64]));
        bb.h[3] = __float22half2_rn(make_float2(base[6*64], base[7*64]));
        bfr[nt][kk] = bb.v;
      }
      b2v[nt] = b2[nt*16 + col];
    }
#pragma unroll 1
    for (int rli = 0; rli < 2; ++rli) {
      int rl = w*2 + rli;                 // this wave owns receivers 2w, 2w+1
      const hf* qrow = QbH + (enc*8 + rl)*64;
      v8hf q0 = *(const v8hf*)(qrow + quad*8);
      v8hf q1 = *(const v8hf*)(qrow + 32 + quad*8);
      const float* etrow = ETl + (enc*8 + rl)*64;
#pragma unroll 2
      for (int st = 0; st < 4; ++st) {
        const hf* prow = PlH + enc*4608 + (st*16 + col)*72 + quad*8;
        v8hf p0 = *(const v8hf*)prow;
        v8hf p1 = *(const v8hf*)(prow + 32);
        v8hf s0 = __builtin_elementwise_max(p0 + q0, zero8);
        v8hf s1 = __builtin_elementwise_max(p1 + q1, zero8);
        float4 etv = *(const float4*)(etrow + st*16 + quad*4);
#pragma unroll
        for (int nt = 0; nt < 4; ++nt) {
          fv4 acc = {b2v[nt], b2v[nt], b2v[nt], b2v[nt]};
          acc = __builtin_amdgcn_mfma_f32_16x16x32_f16(s0, bfr[nt][0], acc, 0, 0, 0);
          acc = __builtin_amdgcn_mfma_f32_16x16x32_f16(s1, bfr[nt][1], acc, 0, 0, 0);
          float m = msgacc[rli][nt];
          m += etv.x * fmaxf(acc[0], 0.f);
          m += etv.y * fmaxf(acc[1], 0.f);
          m += etv.z * fmaxf(acc[2], 0.f);
          m += etv.w * fmaxf(acc[3], 0.f);
          msgacc[rli][nt] = m;
        }
      }
    }
  }
  // quad reduction over senders -> XD msg part (fp16)
#pragma unroll
  for (int rli = 0; rli < 2; ++rli) {
#pragma unroll
    for (int nt = 0; nt < 4; ++nt) {
      float v = msgacc[rli][nt];
      v += __shfl_xor(v, 16);
      v += __shfl_xor(v, 32);
      if (lane < 16) XD[(w*2 + rli)*104 + 16 + nt*16 + lane] = (hf)v;
    }
  }
  __syncthreads();                        // barrier #2

  // ======== decoder via MFMA, wave 0 only ========
  // layer1: C[m=rl][n] = XD(8x96) @ ndw1(96x64, rows>=80 zero), +b1, relu
  // layer2: C[m=rl][o] = HD2(8x64) @ ndw2(64x16), +b2, relu -> out
  if (w == 0) {
    ABh xa[3];
    const hf* xrow = XD + col*104;        // A row = receiver rl (cols 8-15 garbage, rows unused)
#pragma unroll
    for (int kk = 0; kk < 3; ++kk) xa[kk].v = *(const v8hf*)(xrow + kk*32 + quad*8);
#pragma unroll
    for (int ht = 0; ht < 4; ++ht) {
      int cc = ht*16 + col;
      float bias = ndb1[cc];
      fv4 acc = {bias, bias, bias, bias};
#pragma unroll
      for (int kk = 0; kk < 3; ++kk) {
        ABh bb;
#pragma unroll
        for (int j = 0; j < 4; ++j) {
          int rA = kk*32 + quad*8 + 2*j;
          int rB = rA + 1;
          float f0 = ndw1[(rA < 80 ? rA : 79)*64 + cc] * (rA < 80 ? 1.f : 0.f);
          float f1 = ndw1[(rB < 80 ? rB : 79)*64 + cc] * (rB < 80 ? 1.f : 0.f);
          bb.h[j] = __float22half2_rn(make_float2(f0, f1));
        }
        acc = __builtin_amdgcn_mfma_f32_16x16x32_f16(xa[kk].v, bb.v, acc, 0, 0, 0);
      }
      if (quad < 2) {
#pragma unroll
        for (int rr = 0; rr < 4; ++rr)
          HD2[(quad*4 + rr)*104 + cc] = (hf)fmaxf(acc[rr], 0.f);
      }
    }
    // layer2 (same-wave LDS write->read: program order, no barrier needed)
    const hf* hrow = HD2 + col*104;
    v8hf ha0 = *(const v8hf*)(hrow + quad*8);
    v8hf ha1 = *(const v8hf*)(hrow + 32 + quad*8);
    ABh b20, b21;
#pragma unroll
    for (int j = 0; j < 4; ++j) {
      float f0 = ndw2[(quad*8 + 2*j    )*16 + col];
      float f1 = ndw2[(quad*8 + 2*j + 1)*16 + col];
      b20.h[j] = __float22half2_rn(make_float2(f0, f1));
      float g0 = ndw2[(32 + quad*8 + 2*j    )*16 + col];
      float g1 = ndw2[(32 + quad*8 + 2*j + 1)*16 + col];
      b21.h[j] = __float22half2_rn(make_float2(g0, g1));
    }
    float bias2 = ndb2[col];
    fv4 acc2 = {bias2, bias2, bias2, bias2};
    acc2 = __builtin_amdgcn_mfma_f32_16x16x32_f16(ha0, b20.v, acc2, 0, 0, 0);
    acc2 = __builtin_amdgcn_mfma_f32_16x16x32_f16(ha1, b21.v, acc2, 0, 0, 0);
    if (quad < 2) {
#pragma unroll
      for (int rr = 0; rr < 4; ++rr) {
        int rl = quad*4 + rr;
        out[(b*64 + r0 + rl)*16 + col] = fmaxf(acc2[rr], 0.f);
      }
    }
  }
}

extern "C" void kernel_launch(void* const* d_in, const int* in_sizes, int n_in,
                              void* d_out, int out_size, void* d_ws, size_t ws_size,
                              hipStream_t stream) {
  const float* ns   = (const float*)d_in[0];
  const float* et   = (const float*)d_in[1];
  const float* e0w1 = (const float*)d_in[2];
  const float* e0b1 = (const float*)d_in[3];
  const float* e0w2 = (const float*)d_in[4];
  const float* e0b2 = (const float*)d_in[5];
  const float* e1w1 = (const float*)d_in[6];
  const float* e1b1 = (const float*)d_in[7];
  const float* e1w2 = (const float*)d_in[8];
  const float* e1b2 = (const float*)d_in[9];
  const float* ndw1 = (const float*)d_in[10];
  const float* ndb1 = (const float*)d_in[11];
  const float* ndw2 = (const float*)d_in[12];
  const float* ndb2 = (const float*)d_in[13];

  fused_kernel<<<1024, 256, 0, stream>>>(ns, et,
                                         e0w1, e0b1, e0w2, e0b2,
                                         e1w1, e1b1, e1w2, e1b2,
                                         ndw1, ndb1, ndw2, ndb2,
                                         (float*)d_out);
}